// Round 7
// baseline (567.349 us; speedup 1.0000x reference)
//
#include <hip/hip_runtime.h>

#define N_USER 50000
#define N_ITEM 100000
#define NTOT   150000
#define D      64
#define NNZ    2400000
#define NEG_SLOPE 0.01f

#define BSHIFT 10
#define NB     147            // ceil(NTOT / 1024)
#define P1_PER 4096           // entries per block in binning passes (1024 thr x 4)
#define NBLK1  586            // ceil(NNZ / P1_PER)
#define NROWBLK 2344          // ceil(NTOT / 64)

typedef unsigned int uint;
typedef unsigned short ushort;
typedef _Float16 h4 __attribute__((ext_vector_type(4)));
typedef float f4 __attribute__((ext_vector_type(4)));

__device__ inline uint bf16rne(float x) {           // f32 -> bf16 bits (RNE)
    uint b = __float_as_uint(x);
    return (b + 0x7FFFu + ((b >> 16) & 1u)) >> 16;
}
__device__ inline float bf_lo(uint u) { return __uint_as_float(u << 16); }
__device__ inline float bf_hi(uint u) { return __uint_as_float(u & 0xFFFF0000u); }

// ---------------- concat user+item embeddings -> bf16 ego0 ----------------
__global__ void k_concat16(const float* __restrict__ u, const float* __restrict__ it,
                           ushort* __restrict__ A16) {
    int i = blockIdx.x * 256 + threadIdx.x;          // float4 index, exact grid 2.4M
    const int nu4 = N_USER * D / 4;
    float4 v = (i < nu4) ? ((const float4*)u)[i] : ((const float4*)it)[i - nu4];
    uint lo = bf16rne(v.x) | (bf16rne(v.y) << 16);
    uint hi = bf16rne(v.z) | (bf16rne(v.w) << 16);
    ((uint2*)A16)[i] = make_uint2(lo, hi);
}

__global__ void k_bzero(int* __restrict__ bcnt) {
    int t = threadIdx.x;
    if (t < NB) bcnt[t] = 0;
}

// ---------------- bucket histogram (LDS-aggregated) ----------------
__global__ __launch_bounds__(1024) void k_bhist(const int* __restrict__ rows,
                                                int* __restrict__ bcnt) {
    __shared__ int lcnt[NB];
    int tid = threadIdx.x;
    if (tid < NB) lcnt[tid] = 0;
    __syncthreads();
    int base = blockIdx.x * P1_PER;
    #pragma unroll
    for (int k = 0; k < 4; ++k) {
        int i = base + k * 1024 + tid;
        if (i < NNZ) atomicAdd(&lcnt[rows[i] >> BSHIFT], 1);
    }
    __syncthreads();
    if (tid < NB) atomicAdd(&bcnt[tid], lcnt[tid]);
}

__global__ void k_bscan(const int* __restrict__ bcnt, int* __restrict__ bptr,
                        int* __restrict__ bcur) {
    __shared__ int s[256];
    int tid = threadIdx.x;
    int v = (tid < NB) ? bcnt[tid] : 0;
    s[tid] = v; __syncthreads();
    for (int off = 1; off < 256; off <<= 1) {
        int t = (tid >= off) ? s[tid - off] : 0;
        __syncthreads();
        s[tid] += t;
        __syncthreads();
    }
    if (tid < NB) { int ex = s[tid] - v; bptr[tid] = ex; bcur[tid] = ex; }
    if (tid == NB - 1) bptr[NB] = s[tid];
}

// ---------------- pass 1: bin entries bucket-major ----------------
__global__ __launch_bounds__(1024) void k_binpass1(const int* __restrict__ rows,
                                                   const int* __restrict__ cols,
                                                   const float* __restrict__ vals,
                                                   int* __restrict__ bcur,
                                                   int2* __restrict__ bucketed) {
    __shared__ int lcnt[NB], lbase[NB];
    int tid = threadIdx.x;
    int base = blockIdx.x * P1_PER;
    if (tid < NB) lcnt[tid] = 0;
    __syncthreads();
    int r[4];
    #pragma unroll
    for (int k = 0; k < 4; ++k) {
        int i = base + k * 1024 + tid;
        r[k] = (i < NNZ) ? rows[i] : -1;
        if (r[k] >= 0) atomicAdd(&lcnt[r[k] >> BSHIFT], 1);
    }
    __syncthreads();
    if (tid < NB) { lbase[tid] = atomicAdd(&bcur[tid], lcnt[tid]); lcnt[tid] = 0; }
    __syncthreads();
    #pragma unroll
    for (int k = 0; k < 4; ++k) {
        int i = base + k * 1024 + tid;
        if (r[k] >= 0) {
            int b = r[k] >> BSHIFT;
            int off = atomicAdd(&lcnt[b], 1);
            bucketed[lbase[b] + off] =
                make_int2(((r[k] & 1023) << 18) | cols[i], __float_as_int(vals[i]));
        }
    }
}

// ---------------- pass 2: per-bucket CSR build ----------------
__global__ __launch_bounds__(1024) void k_binpass2(const int* __restrict__ bptr,
                                                   const int2* __restrict__ bucketed,
                                                   int* __restrict__ ptr,
                                                   int2* __restrict__ csr) {
    __shared__ int c0[1024], px[1024];
    int tid = threadIdx.x, b = blockIdx.x;
    int s = bptr[b], e = bptr[b + 1];
    c0[tid] = 0;
    __syncthreads();
    for (int i = s + tid; i < e; i += 1024) atomicAdd(&c0[bucketed[i].x >> 18], 1);
    __syncthreads();
    int v = c0[tid];
    px[tid] = v;
    __syncthreads();
    for (int off = 1; off < 1024; off <<= 1) {
        int t = (tid >= off) ? px[tid - off] : 0;
        __syncthreads();
        px[tid] += t;
        __syncthreads();
    }
    int ex = px[tid] - v;
    int r = (b << BSHIFT) + tid;
    if (r <= NTOT) ptr[r] = s + ex;
    px[tid] = ex;
    c0[tid] = 0;
    __syncthreads();
    for (int i = s + tid; i < e; i += 1024) {
        int2 e2 = bucketed[i];
        int lr = e2.x >> 18;
        int off = atomicAdd(&c0[lr], 1);
        csr[s + px[lr] + off] = make_int2(e2.x & 0x3FFFF, e2.y);
    }
}

// ======== fused layer: SpMM + leaky((L+E)@Wgc + (L*E)@Wbi + 2b) -> bf16 ========
// Block = 64 rows (4 waves x 16 rows). Per-wave LDS A-tile, no cross-wave sync
// after W staging. MFMA f32_16x16x16_f16: A lane l -> row l&15, k=(l>>4)*4+j;
// D lane l reg i -> row (l>>4)*4+i, col l&15.
#define XPITCH 136            // f16 row pitch: 64 x1 + 64 x2 + 8 pad (272B, 2-way banks)
__global__ __launch_bounds__(256) void k_layer(
        const int* __restrict__ ptr, const int2* __restrict__ csr,
        const ushort* __restrict__ E16,
        const float* __restrict__ Wgc, const float* __restrict__ Wbi,
        const float* __restrict__ bb, ushort* __restrict__ O16) {
    __shared__ _Float16 ldsW[2 * 16 * 256];     // 16KB: [m][ks*4+nt][n'*16+k']
    __shared__ ushort   xbuf[4][16 * XPITCH];   // per-wave A-tile; aliased as ldsO later
    int tid = threadIdx.x;

    #pragma unroll
    for (int m = 0; m < 2; ++m) {
        const float* W = m ? Wbi : Wgc;
        for (int idx = tid; idx < 4096; idx += 256) {
            int k = idx >> 6, nn = idx & 63;
            ldsW[(m * 16 + (k >> 4) * 4 + (nn >> 4)) * 256 + (nn & 15) * 16 + (k & 15)] =
                (_Float16)W[idx];
        }
    }
    __syncthreads();

    int lane = tid & 63, w = tid >> 6;
    int half = lane >> 5, l32 = lane & 31;
    int g = lane >> 4, r16 = lane & 15;
    const uint* E32 = (const uint*)E16;
    _Float16* xw = (_Float16*)&xbuf[w][0];

    // B-fragments persistent in registers: one ds_read_b64 each
    h4 bfrag[2][4][4];
    #pragma unroll
    for (int m = 0; m < 2; ++m)
        #pragma unroll
        for (int ks = 0; ks < 4; ++ks)
            #pragma unroll
            for (int nt = 0; nt < 4; ++nt)
                bfrag[m][ks][nt] =
                    *(const h4*)&ldsW[(m * 16 + ks * 4 + nt) * 256 + r16 * 16 + g * 4];

    int rowbase = blockIdx.x * 64 + w * 16;

    // ---- phase 1: SpMM 16 rows, write f16 x1/x2 pairs to own LDS tile ----
    for (int i = 0; i < 16; ++i) {
        int r = rowbase + i;
        int rr = __builtin_amdgcn_readfirstlane(min(r, NTOT - 1));
        int start = ptr[rr], end = ptr[rr + 1];
        float acc0 = 0.f, acc1 = 0.f;
        int j = start;
        for (; j + 15 < end; j += 16) {              // named 16-unroll (no scratch!)
            int2 ea0 = csr[j + 0],  ea1 = csr[j + 1],  ea2 = csr[j + 2],  ea3 = csr[j + 3];
            int2 ea4 = csr[j + 4],  ea5 = csr[j + 5],  ea6 = csr[j + 6],  ea7 = csr[j + 7];
            int2 ea8 = csr[j + 8],  ea9 = csr[j + 9],  eaA = csr[j + 10], eaB = csr[j + 11];
            int2 eaC = csr[j + 12], eaD = csr[j + 13], eaE = csr[j + 14], eaF = csr[j + 15];
            int c0 = half ? ea1.x : ea0.x;
            int c1 = half ? ea3.x : ea2.x;
            int c2 = half ? ea5.x : ea4.x;
            int c3 = half ? ea7.x : ea6.x;
            int c4 = half ? ea9.x : ea8.x;
            int c5 = half ? eaB.x : eaA.x;
            int c6 = half ? eaD.x : eaC.x;
            int c7 = half ? eaF.x : eaE.x;
            uint u0 = E32[(c0 << 5) + l32];
            uint u1 = E32[(c1 << 5) + l32];
            uint u2 = E32[(c2 << 5) + l32];
            uint u3 = E32[(c3 << 5) + l32];
            uint u4 = E32[(c4 << 5) + l32];
            uint u5 = E32[(c5 << 5) + l32];
            uint u6 = E32[(c6 << 5) + l32];
            uint u7 = E32[(c7 << 5) + l32];
            float v0 = __int_as_float(half ? ea1.y : ea0.y);
            float v1 = __int_as_float(half ? ea3.y : ea2.y);
            float v2 = __int_as_float(half ? ea5.y : ea4.y);
            float v3 = __int_as_float(half ? ea7.y : ea6.y);
            float v4 = __int_as_float(half ? ea9.y : ea8.y);
            float v5 = __int_as_float(half ? eaB.y : eaA.y);
            float v6 = __int_as_float(half ? eaD.y : eaC.y);
            float v7 = __int_as_float(half ? eaF.y : eaE.y);
            acc0 += v0 * bf_lo(u0);  acc1 += v0 * bf_hi(u0);
            acc0 += v1 * bf_lo(u1);  acc1 += v1 * bf_hi(u1);
            acc0 += v2 * bf_lo(u2);  acc1 += v2 * bf_hi(u2);
            acc0 += v3 * bf_lo(u3);  acc1 += v3 * bf_hi(u3);
            acc0 += v4 * bf_lo(u4);  acc1 += v4 * bf_hi(u4);
            acc0 += v5 * bf_lo(u5);  acc1 += v5 * bf_hi(u5);
            acc0 += v6 * bf_lo(u6);  acc1 += v6 * bf_hi(u6);
            acc0 += v7 * bf_lo(u7);  acc1 += v7 * bf_hi(u7);
        }
        for (; j + 7 < end; j += 8) {
            int2 ea = csr[j + 0], eb = csr[j + 1];
            int2 ec = csr[j + 2], ed = csr[j + 3];
            int2 ee = csr[j + 4], ef = csr[j + 5];
            int2 eg = csr[j + 6], eh = csr[j + 7];
            int c0 = half ? eb.x : ea.x;
            int c1 = half ? ed.x : ec.x;
            int c2 = half ? ef.x : ee.x;
            int c3 = half ? eh.x : eg.x;
            uint u0 = E32[(c0 << 5) + l32];
            uint u1 = E32[(c1 << 5) + l32];
            uint u2 = E32[(c2 << 5) + l32];
            uint u3 = E32[(c3 << 5) + l32];
            float v0 = __int_as_float(half ? eb.y : ea.y);
            float v1 = __int_as_float(half ? ed.y : ec.y);
            float v2 = __int_as_float(half ? ef.y : ee.y);
            float v3 = __int_as_float(half ? eh.y : eg.y);
            acc0 += v0 * bf_lo(u0);  acc1 += v0 * bf_hi(u0);
            acc0 += v1 * bf_lo(u1);  acc1 += v1 * bf_hi(u1);
            acc0 += v2 * bf_lo(u2);  acc1 += v2 * bf_hi(u2);
            acc0 += v3 * bf_lo(u3);  acc1 += v3 * bf_hi(u3);
        }
        for (; j + 1 < end; j += 2) {
            int2 ea = csr[j], eb = csr[j + 1];
            int c   = half ? eb.x : ea.x;
            float v = __int_as_float(half ? eb.y : ea.y);
            uint u = E32[(c << 5) + l32];
            acc0 += v * bf_lo(u);  acc1 += v * bf_hi(u);
        }
        if (j < end) {
            int2 ea = csr[j];
            if (half == 0) {
                uint u = E32[(ea.x << 5) + l32];
                float v = __int_as_float(ea.y);
                acc0 += v * bf_lo(u);  acc1 += v * bf_hi(u);
            }
        }
        acc0 += __shfl_xor(acc0, 32, 64);            // all lanes now hold the sums
        acc1 += __shfl_xor(acc1, 32, 64);

        uint eu = E32[(rr << 5) + l32];              // own-row ego pair
        float e0 = bf_lo(eu), e1 = bf_hi(eu);
        // half 0 writes x1 = L+E at col 2*l32; half 1 writes x2 = L*E at col 64+2*l32
        float p0 = half ? acc0 * e0 : acc0 + e0;
        float p1 = half ? acc1 * e1 : acc1 + e1;
        ushort2 pk;
        pk.x = __builtin_bit_cast(ushort, (_Float16)p0);
        pk.y = __builtin_bit_cast(ushort, (_Float16)p1);
        *(ushort2*)&xw[i * XPITCH + half * 64 + 2 * l32] = pk;
    }

    // ---- phase 2: MFMA 16x64 tile (A from own LDS tile, B in regs) ----
    f4 acc[4];
    #pragma unroll
    for (int nt = 0; nt < 4; ++nt) acc[nt] = (f4){0.f, 0.f, 0.f, 0.f};
    #pragma unroll
    for (int ks = 0; ks < 4; ++ks) {
        h4 a1 = *(const h4*)&xw[r16 * XPITCH + ks * 16 + g * 4];
        #pragma unroll
        for (int nt = 0; nt < 4; ++nt)
            acc[nt] = __builtin_amdgcn_mfma_f32_16x16x16f16(a1, bfrag[0][ks][nt],
                                                            acc[nt], 0, 0, 0);
    }
    #pragma unroll
    for (int ks = 0; ks < 4; ++ks) {
        h4 a2 = *(const h4*)&xw[r16 * XPITCH + 64 + ks * 16 + g * 4];
        #pragma unroll
        for (int nt = 0; nt < 4; ++nt)
            acc[nt] = __builtin_amdgcn_mfma_f32_16x16x16f16(a2, bfrag[1][ks][nt],
                                                            acc[nt], 0, 0, 0);
    }

    // ---- epilogue: bias + leaky -> bf16 via LDS bounce (aliases xbuf) ----
    ushort* ow = &xbuf[w][0];                        // 16 x 72 pitch tile
    #pragma unroll
    for (int nt = 0; nt < 4; ++nt) {
        int col = nt * 16 + r16;
        float bv = 2.f * bb[col];
        #pragma unroll
        for (int i = 0; i < 4; ++i) {
            float y = acc[nt][i] + bv;
            y = (y >= 0.f) ? y : NEG_SLOPE * y;
            ow[(g * 4 + i) * 72 + col] = (ushort)bf16rne(y);
        }
    }
    int lr = lane >> 2;
    int rowg = rowbase + lr;
    if (rowg < NTOT) {
        const ushort* src = &ow[lr * 72 + (lane & 3) * 16];
        uint4 v0 = *(const uint4*)src;
        uint4 v1 = *(const uint4*)(src + 8);
        *(uint4*)&O16[rowg * D + (lane & 3) * 16] = v0;
        *(uint4*)&O16[rowg * D + (lane & 3) * 16 + 8] = v1;
    }
}

// ---------------- gathers into output ----------------
__global__ void k_gather0(const float* __restrict__ u, const float* __restrict__ it,
                          const int* __restrict__ users, const int* __restrict__ pos,
                          const int* __restrict__ neg, float* __restrict__ out) {
    int lane = threadIdx.x & 63;
    int gi = blockIdx.x * 4 + (threadIdx.x >> 6);
    int g = gi >> 12, b = gi & 4095;
    const float* src = (g == 0) ? (u + (size_t)users[b] * D)
                                : (it + (size_t)((g == 1) ? pos[b] : neg[b]) * D);
    out[gi * 256 + lane] = src[lane];
}

__global__ void k_gathern(const ushort* __restrict__ E16, const int* __restrict__ users,
                          const int* __restrict__ pos, const int* __restrict__ neg,
                          float* __restrict__ out, int layer) {
    int lane = threadIdx.x & 63;
    int gi = blockIdx.x * 4 + (threadIdx.x >> 6);
    int g = gi >> 12, b = gi & 4095;
    int src = (g == 0) ? users[b] : (N_USER + ((g == 1) ? pos[b] : neg[b]));
    float v = __uint_as_float(((uint)E16[src * D + lane]) << 16);
    float ss = v * v;
    #pragma unroll
    for (int off = 32; off >= 1; off >>= 1) ss += __shfl_xor(ss, off, 64);
    float dnm = fmaxf(sqrtf(ss), 1e-12f);
    out[gi * 256 + layer * D + lane] = v / dnm;
}

extern "C" void kernel_launch(void* const* d_in, const int* in_sizes, int n_in,
                              void* d_out, int out_size, void* d_ws, size_t ws_size,
                              hipStream_t stream) {
    const float* user_emb = (const float*)d_in[0];
    const float* item_emb = (const float*)d_in[1];
    const float* W_gc     = (const float*)d_in[2];
    const float* W_bi     = (const float*)d_in[3];
    const float* b_bi     = (const float*)d_in[4];
    const float* vals     = (const float*)d_in[5];
    const int*   rows     = (const int*)d_in[6];
    const int*   cols     = (const int*)d_in[7];
    const int*   users    = (const int*)d_in[8];
    const int*   pos      = (const int*)d_in[9];
    const int*   neg      = (const int*)d_in[10];
    float* out = (float*)d_out;

    char* ws = (char*)d_ws;
    size_t off = 0;
    auto alloc = [&](size_t b) { void* p = ws + off; off += (b + 255) & ~(size_t)255; return p; };
    ushort* Ea   = (ushort*)alloc((size_t)NTOT * D * 2);   // bf16 ego (ping)
    ushort* Eb   = (ushort*)alloc((size_t)NTOT * D * 2);   // bf16 ego (pong)
    int2*   csr  = (int2*)  alloc((size_t)NNZ * 8);
    int2*   bucketed = (int2*)alloc((size_t)NNZ * 8);
    int*    ptr  = (int*)   alloc((size_t)(NTOT + 64) * 4);
    int*    bptr = (int*)   alloc((NB + 1) * 4);
    int*    bcnt = (int*)   alloc(NB * 4);
    int*    bcur = (int*)   alloc(NB * 4);
    (void)ws_size;

    hipLaunchKernelGGL(k_concat16, dim3(9375), dim3(256),  0, stream, user_emb, item_emb, Ea);
    hipLaunchKernelGGL(k_bzero,    dim3(1),    dim3(256),  0, stream, bcnt);
    hipLaunchKernelGGL(k_bhist,    dim3(NBLK1),dim3(1024), 0, stream, rows, bcnt);
    hipLaunchKernelGGL(k_bscan,    dim3(1),    dim3(256),  0, stream, bcnt, bptr, bcur);
    hipLaunchKernelGGL(k_binpass1, dim3(NBLK1),dim3(1024), 0, stream, rows, cols, vals, bcur, bucketed);
    hipLaunchKernelGGL(k_binpass2, dim3(NB),   dim3(1024), 0, stream, bptr, bucketed, ptr, csr);
    hipLaunchKernelGGL(k_gather0,  dim3(3072), dim3(256),  0, stream, user_emb, item_emb, users, pos, neg, out);

    ushort* cur = Ea; ushort* nxt = Eb;
    for (int k = 0; k < 3; ++k) {
        hipLaunchKernelGGL(k_layer,   dim3(NROWBLK), dim3(256), 0, stream, ptr, csr, cur,
                           W_gc + k * 4096, W_bi + k * 4096, b_bi + k * 64, nxt);
        hipLaunchKernelGGL(k_gathern, dim3(3072),    dim3(256), 0, stream, nxt, users, pos, neg, out, k + 1);
        ushort* t = cur; cur = nxt; nxt = t;
    }
}

// Round 8
// 453.041 us; speedup vs baseline: 1.2523x; 1.2523x over previous
//
#include <hip/hip_runtime.h>

#define N_USER 50000
#define N_ITEM 100000
#define NTOT   150000
#define D      64
#define NNZ    2400000
#define NEG_SLOPE 0.01f

#define BSHIFT 10
#define NB     147            // ceil(NTOT / 1024)
#define P1_PER 4096           // entries per block in binning passes (1024 thr x 4)
#define NBLK1  586            // ceil(NNZ / P1_PER)
#define NROWBLK 2344          // ceil(NTOT / 64)

typedef unsigned int uint;
typedef unsigned short ushort;
typedef _Float16 h4 __attribute__((ext_vector_type(4)));
typedef float f4 __attribute__((ext_vector_type(4)));

__device__ inline uint bf16rne(float x) {           // f32 -> bf16 bits (RNE)
    uint b = __float_as_uint(x);
    return (b + 0x7FFFu + ((b >> 16) & 1u)) >> 16;
}
__device__ inline float bf_lo(uint u) { return __uint_as_float(u << 16); }
__device__ inline float bf_hi(uint u) { return __uint_as_float(u & 0xFFFF0000u); }

// ---------------- concat user+item embeddings -> bf16 ego0 ----------------
__global__ void k_concat16(const float* __restrict__ u, const float* __restrict__ it,
                           ushort* __restrict__ A16) {
    int i = blockIdx.x * 256 + threadIdx.x;          // float4 index, exact grid 2.4M
    const int nu4 = N_USER * D / 4;
    float4 v = (i < nu4) ? ((const float4*)u)[i] : ((const float4*)it)[i - nu4];
    uint lo = bf16rne(v.x) | (bf16rne(v.y) << 16);
    uint hi = bf16rne(v.z) | (bf16rne(v.w) << 16);
    ((uint2*)A16)[i] = make_uint2(lo, hi);
}

__global__ void k_bzero(int* __restrict__ bcnt) {
    int t = threadIdx.x;
    if (t < NB) bcnt[t] = 0;
}

// ---------------- bucket histogram (LDS-aggregated) ----------------
__global__ __launch_bounds__(1024) void k_bhist(const int* __restrict__ rows,
                                                int* __restrict__ bcnt) {
    __shared__ int lcnt[NB];
    int tid = threadIdx.x;
    if (tid < NB) lcnt[tid] = 0;
    __syncthreads();
    int base = blockIdx.x * P1_PER;
    #pragma unroll
    for (int k = 0; k < 4; ++k) {
        int i = base + k * 1024 + tid;
        if (i < NNZ) atomicAdd(&lcnt[rows[i] >> BSHIFT], 1);
    }
    __syncthreads();
    if (tid < NB) atomicAdd(&bcnt[tid], lcnt[tid]);
}

__global__ void k_bscan(const int* __restrict__ bcnt, int* __restrict__ bptr,
                        int* __restrict__ bcur) {
    __shared__ int s[256];
    int tid = threadIdx.x;
    int v = (tid < NB) ? bcnt[tid] : 0;
    s[tid] = v; __syncthreads();
    for (int off = 1; off < 256; off <<= 1) {
        int t = (tid >= off) ? s[tid - off] : 0;
        __syncthreads();
        s[tid] += t;
        __syncthreads();
    }
    if (tid < NB) { int ex = s[tid] - v; bptr[tid] = ex; bcur[tid] = ex; }
    if (tid == NB - 1) bptr[NB] = s[tid];
}

// ---------------- pass 1: bin entries bucket-major ----------------
__global__ __launch_bounds__(1024) void k_binpass1(const int* __restrict__ rows,
                                                   const int* __restrict__ cols,
                                                   const float* __restrict__ vals,
                                                   int* __restrict__ bcur,
                                                   int2* __restrict__ bucketed) {
    __shared__ int lcnt[NB], lbase[NB];
    int tid = threadIdx.x;
    int base = blockIdx.x * P1_PER;
    if (tid < NB) lcnt[tid] = 0;
    __syncthreads();
    int r[4];
    #pragma unroll
    for (int k = 0; k < 4; ++k) {
        int i = base + k * 1024 + tid;
        r[k] = (i < NNZ) ? rows[i] : -1;
        if (r[k] >= 0) atomicAdd(&lcnt[r[k] >> BSHIFT], 1);
    }
    __syncthreads();
    if (tid < NB) { lbase[tid] = atomicAdd(&bcur[tid], lcnt[tid]); lcnt[tid] = 0; }
    __syncthreads();
    #pragma unroll
    for (int k = 0; k < 4; ++k) {
        int i = base + k * 1024 + tid;
        if (r[k] >= 0) {
            int b = r[k] >> BSHIFT;
            int off = atomicAdd(&lcnt[b], 1);
            bucketed[lbase[b] + off] =
                make_int2(((r[k] & 1023) << 18) | cols[i], __float_as_int(vals[i]));
        }
    }
}

// ---------------- pass 2: per-bucket CSR build ----------------
__global__ __launch_bounds__(1024) void k_binpass2(const int* __restrict__ bptr,
                                                   const int2* __restrict__ bucketed,
                                                   int* __restrict__ ptr,
                                                   int2* __restrict__ csr) {
    __shared__ int c0[1024], px[1024];
    int tid = threadIdx.x, b = blockIdx.x;
    int s = bptr[b], e = bptr[b + 1];
    c0[tid] = 0;
    __syncthreads();
    for (int i = s + tid; i < e; i += 1024) atomicAdd(&c0[bucketed[i].x >> 18], 1);
    __syncthreads();
    int v = c0[tid];
    px[tid] = v;
    __syncthreads();
    for (int off = 1; off < 1024; off <<= 1) {
        int t = (tid >= off) ? px[tid - off] : 0;
        __syncthreads();
        px[tid] += t;
        __syncthreads();
    }
    int ex = px[tid] - v;
    int r = (b << BSHIFT) + tid;
    if (r <= NTOT) ptr[r] = s + ex;
    px[tid] = ex;
    c0[tid] = 0;
    __syncthreads();
    for (int i = s + tid; i < e; i += 1024) {
        int2 e2 = bucketed[i];
        int lr = e2.x >> 18;
        int off = atomicAdd(&c0[lr], 1);
        csr[s + px[lr] + off] = make_int2(e2.x & 0x3FFFF, e2.y);
    }
}

// -------- SpMM: wave/row, scalar CSR broadcast, named 16-entry unroll --------
__global__ __launch_bounds__(256) void k_spmm(const int* __restrict__ ptr,
                                              const int2* __restrict__ csr,
                                              const ushort* __restrict__ E16,
                                              float* __restrict__ Lout) {
    int lane = threadIdx.x & 63;
    int half = lane >> 5;
    int l32  = lane & 31;
    int r = __builtin_amdgcn_readfirstlane(blockIdx.x * 4 + (threadIdx.x >> 6));
    int start = ptr[r], end = ptr[r + 1];
    float acc0 = 0.f, acc1 = 0.f;
    const uint* E32 = (const uint*)E16;              // [c*32 + l32] = cols (2*l32, 2*l32+1)
    int j = start;
    for (; j + 15 < end; j += 16) {                  // 8 gather-lines in flight, all named
        int2 ea0 = csr[j + 0],  ea1 = csr[j + 1],  ea2 = csr[j + 2],  ea3 = csr[j + 3];
        int2 ea4 = csr[j + 4],  ea5 = csr[j + 5],  ea6 = csr[j + 6],  ea7 = csr[j + 7];
        int2 ea8 = csr[j + 8],  ea9 = csr[j + 9],  eaA = csr[j + 10], eaB = csr[j + 11];
        int2 eaC = csr[j + 12], eaD = csr[j + 13], eaE = csr[j + 14], eaF = csr[j + 15];
        int c0 = half ? ea1.x : ea0.x;
        int c1 = half ? ea3.x : ea2.x;
        int c2 = half ? ea5.x : ea4.x;
        int c3 = half ? ea7.x : ea6.x;
        int c4 = half ? ea9.x : ea8.x;
        int c5 = half ? eaB.x : eaA.x;
        int c6 = half ? eaD.x : eaC.x;
        int c7 = half ? eaF.x : eaE.x;
        uint u0 = E32[(c0 << 5) + l32];
        uint u1 = E32[(c1 << 5) + l32];
        uint u2 = E32[(c2 << 5) + l32];
        uint u3 = E32[(c3 << 5) + l32];
        uint u4 = E32[(c4 << 5) + l32];
        uint u5 = E32[(c5 << 5) + l32];
        uint u6 = E32[(c6 << 5) + l32];
        uint u7 = E32[(c7 << 5) + l32];
        float v0 = __int_as_float(half ? ea1.y : ea0.y);
        float v1 = __int_as_float(half ? ea3.y : ea2.y);
        float v2 = __int_as_float(half ? ea5.y : ea4.y);
        float v3 = __int_as_float(half ? ea7.y : ea6.y);
        float v4 = __int_as_float(half ? ea9.y : ea8.y);
        float v5 = __int_as_float(half ? eaB.y : eaA.y);
        float v6 = __int_as_float(half ? eaD.y : eaC.y);
        float v7 = __int_as_float(half ? eaF.y : eaE.y);
        acc0 += v0 * bf_lo(u0);  acc1 += v0 * bf_hi(u0);
        acc0 += v1 * bf_lo(u1);  acc1 += v1 * bf_hi(u1);
        acc0 += v2 * bf_lo(u2);  acc1 += v2 * bf_hi(u2);
        acc0 += v3 * bf_lo(u3);  acc1 += v3 * bf_hi(u3);
        acc0 += v4 * bf_lo(u4);  acc1 += v4 * bf_hi(u4);
        acc0 += v5 * bf_lo(u5);  acc1 += v5 * bf_hi(u5);
        acc0 += v6 * bf_lo(u6);  acc1 += v6 * bf_hi(u6);
        acc0 += v7 * bf_lo(u7);  acc1 += v7 * bf_hi(u7);
    }
    for (; j + 7 < end; j += 8) {
        int2 ea = csr[j + 0], eb = csr[j + 1];
        int2 ec = csr[j + 2], ed = csr[j + 3];
        int2 ee = csr[j + 4], ef = csr[j + 5];
        int2 eg = csr[j + 6], eh = csr[j + 7];
        int c0 = half ? eb.x : ea.x;
        int c1 = half ? ed.x : ec.x;
        int c2 = half ? ef.x : ee.x;
        int c3 = half ? eh.x : eg.x;
        uint u0 = E32[(c0 << 5) + l32];
        uint u1 = E32[(c1 << 5) + l32];
        uint u2 = E32[(c2 << 5) + l32];
        uint u3 = E32[(c3 << 5) + l32];
        float v0 = __int_as_float(half ? eb.y : ea.y);
        float v1 = __int_as_float(half ? ed.y : ec.y);
        float v2 = __int_as_float(half ? ef.y : ee.y);
        float v3 = __int_as_float(half ? eh.y : eg.y);
        acc0 += v0 * bf_lo(u0);  acc1 += v0 * bf_hi(u0);
        acc0 += v1 * bf_lo(u1);  acc1 += v1 * bf_hi(u1);
        acc0 += v2 * bf_lo(u2);  acc1 += v2 * bf_hi(u2);
        acc0 += v3 * bf_lo(u3);  acc1 += v3 * bf_hi(u3);
    }
    for (; j + 1 < end; j += 2) {
        int2 ea = csr[j], eb = csr[j + 1];
        int c   = half ? eb.x : ea.x;
        float v = __int_as_float(half ? eb.y : ea.y);
        uint u = E32[(c << 5) + l32];
        acc0 += v * bf_lo(u);  acc1 += v * bf_hi(u);
    }
    if (j < end) {
        int2 ea = csr[j];
        if (half == 0) {
            uint u = E32[(ea.x << 5) + l32];
            float v = __int_as_float(ea.y);
            acc0 += v * bf_lo(u);  acc1 += v * bf_hi(u);
        }
    }
    acc0 += __shfl_xor(acc0, 32, 64);
    acc1 += __shfl_xor(acc1, 32, 64);
    if (half == 0)
        *(float2*)&Lout[r * D + l32 * 2] = make_float2(acc0, acc1);
}

// ---- MFMA transform: ego_new = leaky((L+E)@Wgc + (L*E)@Wbi + 2b) -> bf16 ----
// One 64-row tile per block (grid 2344) for occupancy; W staged via LDS.
// v_mfma_f32_16x16x16_f16: A lane l -> row l&15, k=(l>>4)*4+j;
// D lane l reg i -> row (l>>4)*4+i, col l&15.
__global__ __launch_bounds__(256) void k_transform_mfma(
        const ushort* __restrict__ E16, const float* __restrict__ L,
        const float* __restrict__ Wgc, const float* __restrict__ Wbi,
        const float* __restrict__ bb, ushort* __restrict__ O16, int n) {
    __shared__ _Float16 ldsW[2 * 16 * 256];   // 16KB: [m][ks*4+nt][n'*16+k'] (k' contiguous)
    __shared__ ushort   ldsO[4][16 * 72];     // per-wave 16x64 bf16 tile, pitch 72 (144B)
    int tid = threadIdx.x;

    #pragma unroll
    for (int m = 0; m < 2; ++m) {
        const float* W = m ? Wbi : Wgc;
        for (int idx = tid; idx < 4096; idx += 256) {
            int k = idx >> 6, nn = idx & 63;
            ldsW[(m * 16 + (k >> 4) * 4 + (nn >> 4)) * 256 + (nn & 15) * 16 + (k & 15)] =
                (_Float16)W[idx];
        }
    }
    __syncthreads();

    int l = tid & 63, w = tid >> 6;
    int g = l >> 4, r16 = l & 15;

    // B-fragments: one ds_read_b64 each, persistent in registers
    h4 bfrag[2][4][4];
    #pragma unroll
    for (int m = 0; m < 2; ++m)
        #pragma unroll
        for (int ks = 0; ks < 4; ++ks)
            #pragma unroll
            for (int nt = 0; nt < 4; ++nt)
                bfrag[m][ks][nt] =
                    *(const h4*)&ldsW[(m * 16 + ks * 4 + nt) * 256 + r16 * 16 + g * 4];

    int rowbase = blockIdx.x * 64 + w * 16;
    int r = rowbase + r16;
    int rc = min(r, n - 1);

    h4 x1[4], x2[4];
    #pragma unroll
    for (int ks = 0; ks < 4; ++ks) {
        int c = ks * 16 + g * 4;
        float4 lf = *(const float4*)&L[rc * D + c];
        uint2  eu = *(const uint2*)&E16[rc * D + c];
        float e0 = bf_lo(eu.x), e1 = bf_hi(eu.x);
        float e2 = bf_lo(eu.y), e3 = bf_hi(eu.y);
        x1[ks][0] = (_Float16)(lf.x + e0); x1[ks][1] = (_Float16)(lf.y + e1);
        x1[ks][2] = (_Float16)(lf.z + e2); x1[ks][3] = (_Float16)(lf.w + e3);
        x2[ks][0] = (_Float16)(lf.x * e0); x2[ks][1] = (_Float16)(lf.y * e1);
        x2[ks][2] = (_Float16)(lf.z * e2); x2[ks][3] = (_Float16)(lf.w * e3);
    }

    f4 acc[4];
    #pragma unroll
    for (int nt = 0; nt < 4; ++nt) acc[nt] = (f4){0.f, 0.f, 0.f, 0.f};
    #pragma unroll
    for (int ks = 0; ks < 4; ++ks)
        #pragma unroll
        for (int nt = 0; nt < 4; ++nt)
            acc[nt] = __builtin_amdgcn_mfma_f32_16x16x16f16(x1[ks], bfrag[0][ks][nt],
                                                            acc[nt], 0, 0, 0);
    #pragma unroll
    for (int ks = 0; ks < 4; ++ks)
        #pragma unroll
        for (int nt = 0; nt < 4; ++nt)
            acc[nt] = __builtin_amdgcn_mfma_f32_16x16x16f16(x2[ks], bfrag[1][ks][nt],
                                                            acc[nt], 0, 0, 0);

    // epilogue: bias + leaky -> bf16 LDS tile -> coalesced store
    #pragma unroll
    for (int nt = 0; nt < 4; ++nt) {
        int col = nt * 16 + r16;
        float bv = 2.f * bb[col];
        #pragma unroll
        for (int i = 0; i < 4; ++i) {
            float y = acc[nt][i] + bv;
            y = (y >= 0.f) ? y : NEG_SLOPE * y;
            ldsO[w][(g * 4 + i) * 72 + col] = (ushort)bf16rne(y);
        }
    }
    int lr = l >> 2;
    int rowg = rowbase + lr;
    if (rowg < n) {
        const ushort* src = &ldsO[w][lr * 72 + (l & 3) * 16];
        uint4 v0 = *(const uint4*)src;
        uint4 v1 = *(const uint4*)(src + 8);
        *(uint4*)&O16[rowg * D + (l & 3) * 16] = v0;
        *(uint4*)&O16[rowg * D + (l & 3) * 16 + 8] = v1;
    }
}

// ---------------- gathers into output ----------------
__global__ void k_gather0(const float* __restrict__ u, const float* __restrict__ it,
                          const int* __restrict__ users, const int* __restrict__ pos,
                          const int* __restrict__ neg, float* __restrict__ out) {
    int lane = threadIdx.x & 63;
    int gi = blockIdx.x * 4 + (threadIdx.x >> 6);
    int g = gi >> 12, b = gi & 4095;
    const float* src = (g == 0) ? (u + (size_t)users[b] * D)
                                : (it + (size_t)((g == 1) ? pos[b] : neg[b]) * D);
    out[gi * 256 + lane] = src[lane];
}

__global__ void k_gathern(const ushort* __restrict__ E16, const int* __restrict__ users,
                          const int* __restrict__ pos, const int* __restrict__ neg,
                          float* __restrict__ out, int layer) {
    int lane = threadIdx.x & 63;
    int gi = blockIdx.x * 4 + (threadIdx.x >> 6);
    int g = gi >> 12, b = gi & 4095;
    int src = (g == 0) ? users[b] : (N_USER + ((g == 1) ? pos[b] : neg[b]));
    float v = __uint_as_float(((uint)E16[src * D + lane]) << 16);
    float ss = v * v;
    #pragma unroll
    for (int off = 32; off >= 1; off >>= 1) ss += __shfl_xor(ss, off, 64);
    float dnm = fmaxf(sqrtf(ss), 1e-12f);
    out[gi * 256 + layer * D + lane] = v / dnm;
}

extern "C" void kernel_launch(void* const* d_in, const int* in_sizes, int n_in,
                              void* d_out, int out_size, void* d_ws, size_t ws_size,
                              hipStream_t stream) {
    const float* user_emb = (const float*)d_in[0];
    const float* item_emb = (const float*)d_in[1];
    const float* W_gc     = (const float*)d_in[2];
    const float* W_bi     = (const float*)d_in[3];
    const float* b_bi     = (const float*)d_in[4];
    const float* vals     = (const float*)d_in[5];
    const int*   rows     = (const int*)d_in[6];
    const int*   cols     = (const int*)d_in[7];
    const int*   users    = (const int*)d_in[8];
    const int*   pos      = (const int*)d_in[9];
    const int*   neg      = (const int*)d_in[10];
    float* out = (float*)d_out;

    char* ws = (char*)d_ws;
    size_t off = 0;
    auto alloc = [&](size_t b) { void* p = ws + off; off += (b + 255) & ~(size_t)255; return p; };
    ushort* Ea  = (ushort*)alloc((size_t)NTOT * D * 2);   // bf16 ego (ping)
    ushort* Eb  = (ushort*)alloc((size_t)NTOT * D * 2);   // bf16 ego (pong)
    float*  L   = (float*) alloc((size_t)NTOT * D * 4);   // f32 spmm output
    int2*   csr = (int2*)  alloc((size_t)NNZ * 8);
    int*    ptr = (int*)   alloc((size_t)(NTOT + 64) * 4);
    int*    bptr= (int*)   alloc((NB + 1) * 4);
    int*    bcnt= (int*)   alloc(NB * 4);
    int*    bcur= (int*)   alloc(NB * 4);
    int2*   bucketed = (int2*)L;   // alias: dead before first spmm writes L
    (void)ws_size;

    hipLaunchKernelGGL(k_concat16, dim3(9375), dim3(256),  0, stream, user_emb, item_emb, Ea);
    hipLaunchKernelGGL(k_bzero,    dim3(1),    dim3(256),  0, stream, bcnt);
    hipLaunchKernelGGL(k_bhist,    dim3(NBLK1),dim3(1024), 0, stream, rows, bcnt);
    hipLaunchKernelGGL(k_bscan,    dim3(1),    dim3(256),  0, stream, bcnt, bptr, bcur);
    hipLaunchKernelGGL(k_binpass1, dim3(NBLK1),dim3(1024), 0, stream, rows, cols, vals, bcur, bucketed);
    hipLaunchKernelGGL(k_binpass2, dim3(NB),   dim3(1024), 0, stream, bptr, bucketed, ptr, csr);
    hipLaunchKernelGGL(k_gather0,  dim3(3072), dim3(256),  0, stream, user_emb, item_emb, users, pos, neg, out);

    ushort* cur = Ea; ushort* nxt = Eb;
    for (int k = 0; k < 3; ++k) {
        hipLaunchKernelGGL(k_spmm,           dim3(37500),  dim3(256), 0, stream, ptr, csr, cur, L);
        hipLaunchKernelGGL(k_transform_mfma, dim3(NROWBLK),dim3(256), 0, stream, cur, L,
                           W_gc + k * 4096, W_bi + k * 4096, b_bi + k * 64, nxt, NTOT);
        hipLaunchKernelGGL(k_gathern,        dim3(3072),   dim3(256), 0, stream, nxt, users, pos, neg, out, k + 1);
        ushort* t = cur; cur = nxt; nxt = t;
    }
}

// Round 9
// 450.334 us; speedup vs baseline: 1.2598x; 1.0060x over previous
//
#include <hip/hip_runtime.h>

#define N_USER 50000
#define N_ITEM 100000
#define NTOT   150000
#define D      64
#define NNZ    2400000
#define NEG_SLOPE 0.01f

#define BSHIFT 10
#define NB     147            // ceil(NTOT / 1024)
#define P1_PER 4096           // entries per block in binning passes (1024 thr x 4)
#define NBLK1  586            // ceil(NNZ / P1_PER)
#define NROWBLK 2344          // ceil(NTOT / 64)

typedef unsigned int uint;
typedef unsigned short ushort;
typedef _Float16 h2 __attribute__((ext_vector_type(2)));
typedef _Float16 h4 __attribute__((ext_vector_type(4)));
typedef float f4 __attribute__((ext_vector_type(4)));

// ---------------- concat user+item embeddings -> f16 ego0 (+ zero bcnt) ----------------
__global__ void k_concat16(const float* __restrict__ u, const float* __restrict__ it,
                           ushort* __restrict__ A16, int* __restrict__ bcnt) {
    if (blockIdx.x == 0 && threadIdx.x < NB) bcnt[threadIdx.x] = 0;
    int i = blockIdx.x * 256 + threadIdx.x;          // float4 index, exact grid 2.4M
    const int nu4 = N_USER * D / 4;
    float4 v = (i < nu4) ? ((const float4*)u)[i] : ((const float4*)it)[i - nu4];
    h2 a, b;
    a.x = (_Float16)v.x; a.y = (_Float16)v.y;
    b.x = (_Float16)v.z; b.y = (_Float16)v.w;
    ((uint2*)A16)[i] = make_uint2(__builtin_bit_cast(uint, a), __builtin_bit_cast(uint, b));
}

// ---------------- bucket histogram (LDS-aggregated) ----------------
__global__ __launch_bounds__(1024) void k_bhist(const int* __restrict__ rows,
                                                int* __restrict__ bcnt) {
    __shared__ int lcnt[NB];
    int tid = threadIdx.x;
    if (tid < NB) lcnt[tid] = 0;
    __syncthreads();
    int base = blockIdx.x * P1_PER;
    #pragma unroll
    for (int k = 0; k < 4; ++k) {
        int i = base + k * 1024 + tid;
        if (i < NNZ) atomicAdd(&lcnt[rows[i] >> BSHIFT], 1);
    }
    __syncthreads();
    if (tid < NB) atomicAdd(&bcnt[tid], lcnt[tid]);
}

// ---- bscan (block 3072) fused with gather0 (blocks 0..3071): saves a node ----
__global__ void k_bscan_gather(const int* __restrict__ bcnt, int* __restrict__ bptr,
                               int* __restrict__ bcur,
                               const float* __restrict__ u, const float* __restrict__ it,
                               const int* __restrict__ users, const int* __restrict__ pos,
                               const int* __restrict__ neg, float* __restrict__ out) {
    __shared__ int s[256];
    if (blockIdx.x == 3072) {                        // exclusive scan over NB counts
        int tid = threadIdx.x;
        int v = (tid < NB) ? bcnt[tid] : 0;
        s[tid] = v; __syncthreads();
        for (int off = 1; off < 256; off <<= 1) {
            int t = (tid >= off) ? s[tid - off] : 0;
            __syncthreads();
            s[tid] += t;
            __syncthreads();
        }
        if (tid < NB) { int ex = s[tid] - v; bptr[tid] = ex; bcur[tid] = ex; }
        if (tid == NB - 1) bptr[NB] = s[tid];
        return;
    }
    int lane = threadIdx.x & 63;
    int gi = blockIdx.x * 4 + (threadIdx.x >> 6);
    int g = gi >> 12, b = gi & 4095;
    const float* src = (g == 0) ? (u + (size_t)users[b] * D)
                                : (it + (size_t)((g == 1) ? pos[b] : neg[b]) * D);
    out[gi * 256 + lane] = src[lane];
}

// ---------------- pass 1: bin entries bucket-major ----------------
__global__ __launch_bounds__(1024) void k_binpass1(const int* __restrict__ rows,
                                                   const int* __restrict__ cols,
                                                   const float* __restrict__ vals,
                                                   int* __restrict__ bcur,
                                                   int2* __restrict__ bucketed) {
    __shared__ int lcnt[NB], lbase[NB];
    int tid = threadIdx.x;
    int base = blockIdx.x * P1_PER;
    if (tid < NB) lcnt[tid] = 0;
    __syncthreads();
    int r[4];
    #pragma unroll
    for (int k = 0; k < 4; ++k) {
        int i = base + k * 1024 + tid;
        r[k] = (i < NNZ) ? rows[i] : -1;
        if (r[k] >= 0) atomicAdd(&lcnt[r[k] >> BSHIFT], 1);
    }
    __syncthreads();
    if (tid < NB) { lbase[tid] = atomicAdd(&bcur[tid], lcnt[tid]); lcnt[tid] = 0; }
    __syncthreads();
    #pragma unroll
    for (int k = 0; k < 4; ++k) {
        int i = base + k * 1024 + tid;
        if (r[k] >= 0) {
            int b = r[k] >> BSHIFT;
            int off = atomicAdd(&lcnt[b], 1);
            bucketed[lbase[b] + off] =
                make_int2(((r[k] & 1023) << 18) | cols[i], __float_as_int(vals[i]));
        }
    }
}

// ---------------- pass 2: per-bucket CSR build ----------------
__global__ __launch_bounds__(1024) void k_binpass2(const int* __restrict__ bptr,
                                                   const int2* __restrict__ bucketed,
                                                   int* __restrict__ ptr,
                                                   int2* __restrict__ csr) {
    __shared__ int c0[1024], px[1024];
    int tid = threadIdx.x, b = blockIdx.x;
    int s = bptr[b], e = bptr[b + 1];
    c0[tid] = 0;
    __syncthreads();
    for (int i = s + tid; i < e; i += 1024) atomicAdd(&c0[bucketed[i].x >> 18], 1);
    __syncthreads();
    int v = c0[tid];
    px[tid] = v;
    __syncthreads();
    for (int off = 1; off < 1024; off <<= 1) {
        int t = (tid >= off) ? px[tid - off] : 0;
        __syncthreads();
        px[tid] += t;
        __syncthreads();
    }
    int ex = px[tid] - v;
    int r = (b << BSHIFT) + tid;
    if (r <= NTOT) ptr[r] = s + ex;
    px[tid] = ex;
    c0[tid] = 0;
    __syncthreads();
    for (int i = s + tid; i < e; i += 1024) {
        int2 e2 = bucketed[i];
        int lr = e2.x >> 18;
        int off = atomicAdd(&c0[lr], 1);
        csr[s + px[lr] + off] = make_int2(e2.x & 0x3FFFF, e2.y);
    }
}

// -------- SpMM: wave/row, scalar CSR broadcast, f16 gathers + fma_mix, f16 L out --------
__global__ __launch_bounds__(256) void k_spmm(const int* __restrict__ ptr,
                                              const int2* __restrict__ csr,
                                              const ushort* __restrict__ E16,
                                              ushort* __restrict__ L16) {
    int lane = threadIdx.x & 63;
    int half = lane >> 5;
    int l32  = lane & 31;
    int r = __builtin_amdgcn_readfirstlane(blockIdx.x * 4 + (threadIdx.x >> 6));
    int start = ptr[r], end = ptr[r + 1];
    float acc0 = 0.f, acc1 = 0.f;
    const uint* E32 = (const uint*)E16;              // [c*32 + l32] = cols (2*l32, 2*l32+1)
    int j = start;
    for (; j + 15 < end; j += 16) {                  // 8 gather-lines in flight, all named
        int2 ea0 = csr[j + 0],  ea1 = csr[j + 1],  ea2 = csr[j + 2],  ea3 = csr[j + 3];
        int2 ea4 = csr[j + 4],  ea5 = csr[j + 5],  ea6 = csr[j + 6],  ea7 = csr[j + 7];
        int2 ea8 = csr[j + 8],  ea9 = csr[j + 9],  eaA = csr[j + 10], eaB = csr[j + 11];
        int2 eaC = csr[j + 12], eaD = csr[j + 13], eaE = csr[j + 14], eaF = csr[j + 15];
        int c0 = half ? ea1.x : ea0.x;
        int c1 = half ? ea3.x : ea2.x;
        int c2 = half ? ea5.x : ea4.x;
        int c3 = half ? ea7.x : ea6.x;
        int c4 = half ? ea9.x : ea8.x;
        int c5 = half ? eaB.x : eaA.x;
        int c6 = half ? eaD.x : eaC.x;
        int c7 = half ? eaF.x : eaE.x;
        uint u0 = E32[(c0 << 5) + l32];
        uint u1 = E32[(c1 << 5) + l32];
        uint u2 = E32[(c2 << 5) + l32];
        uint u3 = E32[(c3 << 5) + l32];
        uint u4 = E32[(c4 << 5) + l32];
        uint u5 = E32[(c5 << 5) + l32];
        uint u6 = E32[(c6 << 5) + l32];
        uint u7 = E32[(c7 << 5) + l32];
        float v0 = __int_as_float(half ? ea1.y : ea0.y);
        float v1 = __int_as_float(half ? ea3.y : ea2.y);
        float v2 = __int_as_float(half ? ea5.y : ea4.y);
        float v3 = __int_as_float(half ? ea7.y : ea6.y);
        float v4 = __int_as_float(half ? ea9.y : ea8.y);
        float v5 = __int_as_float(half ? eaB.y : eaA.y);
        float v6 = __int_as_float(half ? eaD.y : eaC.y);
        float v7 = __int_as_float(half ? eaF.y : eaE.y);
        h2 p0 = __builtin_bit_cast(h2, u0), p1 = __builtin_bit_cast(h2, u1);
        h2 p2 = __builtin_bit_cast(h2, u2), p3 = __builtin_bit_cast(h2, u3);
        h2 p4 = __builtin_bit_cast(h2, u4), p5 = __builtin_bit_cast(h2, u5);
        h2 p6 = __builtin_bit_cast(h2, u6), p7 = __builtin_bit_cast(h2, u7);
        acc0 += v0 * (float)p0.x;  acc1 += v0 * (float)p0.y;   // v_fma_mix_f32
        acc0 += v1 * (float)p1.x;  acc1 += v1 * (float)p1.y;
        acc0 += v2 * (float)p2.x;  acc1 += v2 * (float)p2.y;
        acc0 += v3 * (float)p3.x;  acc1 += v3 * (float)p3.y;
        acc0 += v4 * (float)p4.x;  acc1 += v4 * (float)p4.y;
        acc0 += v5 * (float)p5.x;  acc1 += v5 * (float)p5.y;
        acc0 += v6 * (float)p6.x;  acc1 += v6 * (float)p6.y;
        acc0 += v7 * (float)p7.x;  acc1 += v7 * (float)p7.y;
    }
    for (; j + 7 < end; j += 8) {
        int2 ea = csr[j + 0], eb = csr[j + 1];
        int2 ec = csr[j + 2], ed = csr[j + 3];
        int2 ee = csr[j + 4], ef = csr[j + 5];
        int2 eg = csr[j + 6], eh = csr[j + 7];
        int c0 = half ? eb.x : ea.x;
        int c1 = half ? ed.x : ec.x;
        int c2 = half ? ef.x : ee.x;
        int c3 = half ? eh.x : eg.x;
        uint u0 = E32[(c0 << 5) + l32];
        uint u1 = E32[(c1 << 5) + l32];
        uint u2 = E32[(c2 << 5) + l32];
        uint u3 = E32[(c3 << 5) + l32];
        float v0 = __int_as_float(half ? eb.y : ea.y);
        float v1 = __int_as_float(half ? ed.y : ec.y);
        float v2 = __int_as_float(half ? ef.y : ee.y);
        float v3 = __int_as_float(half ? eh.y : eg.y);
        h2 p0 = __builtin_bit_cast(h2, u0), p1 = __builtin_bit_cast(h2, u1);
        h2 p2 = __builtin_bit_cast(h2, u2), p3 = __builtin_bit_cast(h2, u3);
        acc0 += v0 * (float)p0.x;  acc1 += v0 * (float)p0.y;
        acc0 += v1 * (float)p1.x;  acc1 += v1 * (float)p1.y;
        acc0 += v2 * (float)p2.x;  acc1 += v2 * (float)p2.y;
        acc0 += v3 * (float)p3.x;  acc1 += v3 * (float)p3.y;
    }
    for (; j + 1 < end; j += 2) {
        int2 ea = csr[j], eb = csr[j + 1];
        int c   = half ? eb.x : ea.x;
        float v = __int_as_float(half ? eb.y : ea.y);
        h2 p = __builtin_bit_cast(h2, E32[(c << 5) + l32]);
        acc0 += v * (float)p.x;  acc1 += v * (float)p.y;
    }
    if (j < end) {
        int2 ea = csr[j];
        if (half == 0) {
            h2 p = __builtin_bit_cast(h2, E32[(ea.x << 5) + l32]);
            float v = __int_as_float(ea.y);
            acc0 += v * (float)p.x;  acc1 += v * (float)p.y;
        }
    }
    acc0 += __shfl_xor(acc0, 32, 64);
    acc1 += __shfl_xor(acc1, 32, 64);
    if (half == 0) {
        h2 o; o.x = (_Float16)acc0; o.y = (_Float16)acc1;
        ((uint*)L16)[(r << 5) + l32] = __builtin_bit_cast(uint, o);
    }
}

// ---- MFMA transform: ego_new = leaky((L+E)@Wgc + (L*E)@Wbi + 2b) -> f16 ----
// v_mfma_f32_16x16x16_f16: A lane l -> row l&15, k=(l>>4)*4+j;
// D lane l reg i -> row (l>>4)*4+i, col l&15.
__global__ __launch_bounds__(256) void k_transform_mfma(
        const ushort* __restrict__ E16, const ushort* __restrict__ L16,
        const float* __restrict__ Wgc, const float* __restrict__ Wbi,
        const float* __restrict__ bb, ushort* __restrict__ O16, int n) {
    __shared__ _Float16 ldsW[2 * 16 * 256];   // 16KB: [m][ks*4+nt][n'*16+k'] (k' contiguous)
    __shared__ ushort   ldsO[4][16 * 72];     // per-wave 16x64 f16 tile, pitch 72 (144B)
    int tid = threadIdx.x;

    #pragma unroll
    for (int m = 0; m < 2; ++m) {
        const float* W = m ? Wbi : Wgc;
        for (int idx = tid; idx < 4096; idx += 256) {
            int k = idx >> 6, nn = idx & 63;
            ldsW[(m * 16 + (k >> 4) * 4 + (nn >> 4)) * 256 + (nn & 15) * 16 + (k & 15)] =
                (_Float16)W[idx];
        }
    }
    __syncthreads();

    int l = tid & 63, w = tid >> 6;
    int g = l >> 4, r16 = l & 15;

    // B-fragments: one ds_read_b64 each, persistent in registers
    h4 bfrag[2][4][4];
    #pragma unroll
    for (int m = 0; m < 2; ++m)
        #pragma unroll
        for (int ks = 0; ks < 4; ++ks)
            #pragma unroll
            for (int nt = 0; nt < 4; ++nt)
                bfrag[m][ks][nt] =
                    *(const h4*)&ldsW[(m * 16 + ks * 4 + nt) * 256 + r16 * 16 + g * 4];

    int rowbase = blockIdx.x * 64 + w * 16;
    int r = rowbase + r16;
    int rc = min(r, n - 1);

    h4 x1[4], x2[4];
    #pragma unroll
    for (int ks = 0; ks < 4; ++ks) {
        int ui = (rc << 5) + ks * 8 + g * 2;         // uint index: 4 f16 = uint2
        uint2 lw = *(const uint2*)&((const uint*)L16)[ui];
        uint2 ew = *(const uint2*)&((const uint*)E16)[ui];
        h4 l4, e4;
        h2 la = __builtin_bit_cast(h2, lw.x), lb = __builtin_bit_cast(h2, lw.y);
        h2 ea = __builtin_bit_cast(h2, ew.x), eb = __builtin_bit_cast(h2, ew.y);
        l4[0] = la.x; l4[1] = la.y; l4[2] = lb.x; l4[3] = lb.y;
        e4[0] = ea.x; e4[1] = ea.y; e4[2] = eb.x; e4[3] = eb.y;
        x1[ks] = l4 + e4;                            // v_pk_add_f16
        x2[ks] = l4 * e4;                            // v_pk_mul_f16
    }

    f4 acc[4];
    #pragma unroll
    for (int nt = 0; nt < 4; ++nt) acc[nt] = (f4){0.f, 0.f, 0.f, 0.f};
    #pragma unroll
    for (int ks = 0; ks < 4; ++ks)
        #pragma unroll
        for (int nt = 0; nt < 4; ++nt)
            acc[nt] = __builtin_amdgcn_mfma_f32_16x16x16f16(x1[ks], bfrag[0][ks][nt],
                                                            acc[nt], 0, 0, 0);
    #pragma unroll
    for (int ks = 0; ks < 4; ++ks)
        #pragma unroll
        for (int nt = 0; nt < 4; ++nt)
            acc[nt] = __builtin_amdgcn_mfma_f32_16x16x16f16(x2[ks], bfrag[1][ks][nt],
                                                            acc[nt], 0, 0, 0);

    // epilogue: bias + leaky -> f16 LDS tile -> coalesced store
    #pragma unroll
    for (int nt = 0; nt < 4; ++nt) {
        int col = nt * 16 + r16;
        float bv = 2.f * bb[col];
        #pragma unroll
        for (int i = 0; i < 4; ++i) {
            float y = acc[nt][i] + bv;
            y = (y >= 0.f) ? y : NEG_SLOPE * y;
            ldsO[w][(g * 4 + i) * 72 + col] = __builtin_bit_cast(ushort, (_Float16)y);
        }
    }
    int lr = l >> 2;
    int rowg = rowbase + lr;
    if (rowg < n) {
        const ushort* src = &ldsO[w][lr * 72 + (l & 3) * 16];
        uint4 v0 = *(const uint4*)src;
        uint4 v1 = *(const uint4*)(src + 8);
        *(uint4*)&O16[rowg * D + (l & 3) * 16] = v0;
        *(uint4*)&O16[rowg * D + (l & 3) * 16 + 8] = v1;
    }
}

// ---------------- normalized gather (f16 ego) ----------------
__global__ void k_gathern(const ushort* __restrict__ E16, const int* __restrict__ users,
                          const int* __restrict__ pos, const int* __restrict__ neg,
                          float* __restrict__ out, int layer) {
    int lane = threadIdx.x & 63;
    int gi = blockIdx.x * 4 + (threadIdx.x >> 6);
    int g = gi >> 12, b = gi & 4095;
    int src = (g == 0) ? users[b] : (N_USER + ((g == 1) ? pos[b] : neg[b]));
    float v = (float)__builtin_bit_cast(_Float16, E16[src * D + lane]);
    float ss = v * v;
    #pragma unroll
    for (int off = 32; off >= 1; off >>= 1) ss += __shfl_xor(ss, off, 64);
    float dnm = fmaxf(sqrtf(ss), 1e-12f);
    out[gi * 256 + layer * D + lane] = v / dnm;
}

extern "C" void kernel_launch(void* const* d_in, const int* in_sizes, int n_in,
                              void* d_out, int out_size, void* d_ws, size_t ws_size,
                              hipStream_t stream) {
    const float* user_emb = (const float*)d_in[0];
    const float* item_emb = (const float*)d_in[1];
    const float* W_gc     = (const float*)d_in[2];
    const float* W_bi     = (const float*)d_in[3];
    const float* b_bi     = (const float*)d_in[4];
    const float* vals     = (const float*)d_in[5];
    const int*   rows     = (const int*)d_in[6];
    const int*   cols     = (const int*)d_in[7];
    const int*   users    = (const int*)d_in[8];
    const int*   pos      = (const int*)d_in[9];
    const int*   neg      = (const int*)d_in[10];
    float* out = (float*)d_out;

    char* ws = (char*)d_ws;
    size_t off = 0;
    auto alloc = [&](size_t b) { void* p = ws + off; off += (b + 255) & ~(size_t)255; return p; };
    ushort* Ea  = (ushort*)alloc((size_t)NTOT * D * 2);   // f16 ego (ping)
    ushort* Eb  = (ushort*)alloc((size_t)NTOT * D * 2);   // f16 ego (pong)
    ushort* L16 = (ushort*)alloc((size_t)NTOT * D * 2);   // f16 spmm output
    int2*   csr = (int2*)  alloc((size_t)NNZ * 8);
    int*    ptr = (int*)   alloc((size_t)(NTOT + 64) * 4);
    int*    bptr= (int*)   alloc((NB + 1) * 4);
    int*    bcnt= (int*)   alloc(NB * 4);
    int*    bcur= (int*)   alloc(NB * 4);
    int2*   bucketed = (int2*)alloc((size_t)NNZ * 8);     // dead after binpass2
    (void)ws_size;

    hipLaunchKernelGGL(k_concat16,    dim3(9375), dim3(256),  0, stream, user_emb, item_emb, Ea, bcnt);
    hipLaunchKernelGGL(k_bhist,       dim3(NBLK1),dim3(1024), 0, stream, rows, bcnt);
    hipLaunchKernelGGL(k_bscan_gather,dim3(3073), dim3(256),  0, stream, bcnt, bptr, bcur,
                       user_emb, item_emb, users, pos, neg, out);
    hipLaunchKernelGGL(k_binpass1,    dim3(NBLK1),dim3(1024), 0, stream, rows, cols, vals, bcur, bucketed);
    hipLaunchKernelGGL(k_binpass2,    dim3(NB),   dim3(1024), 0, stream, bptr, bucketed, ptr, csr);

    ushort* cur = Ea; ushort* nxt = Eb;
    for (int k = 0; k < 3; ++k) {
        hipLaunchKernelGGL(k_spmm,           dim3(37500),  dim3(256), 0, stream, ptr, csr, cur, L16);
        hipLaunchKernelGGL(k_transform_mfma, dim3(NROWBLK),dim3(256), 0, stream, cur, L16,
                           W_gc + k * 4096, W_bi + k * 4096, b_bi + k * 64, nxt, NTOT);
        hipLaunchKernelGGL(k_gathern,        dim3(3072),   dim3(256), 0, stream, nxt, users, pos, neg, out, k + 1);
        ushort* t = cur; cur = nxt; nxt = t;
    }
}

// Round 10
// 444.912 us; speedup vs baseline: 1.2752x; 1.0122x over previous
//
#include <hip/hip_runtime.h>

#define N_USER 50000
#define N_ITEM 100000
#define NTOT   150000
#define D      64
#define NNZ    2400000
#define NEG_SLOPE 0.01f

#define BSHIFT 10
#define NB     147            // ceil(NTOT / 1024)
#define P1_PER 4096           // entries per block in binning passes (1024 thr x 4)
#define NBLK1  586            // ceil(NNZ / P1_PER)
#define NROWBLK 2344          // ceil(NTOT / 64)
#define SPMM_BLKS 37500

typedef unsigned int uint;
typedef unsigned short ushort;
typedef _Float16 h2 __attribute__((ext_vector_type(2)));
typedef _Float16 h4 __attribute__((ext_vector_type(4)));
typedef float f4 __attribute__((ext_vector_type(4)));

// ---------------- concat user+item embeddings -> f16 ego0 (+ zero bcnt) ----------------
__global__ void k_concat16(const float* __restrict__ u, const float* __restrict__ it,
                           ushort* __restrict__ A16, int* __restrict__ bcnt) {
    if (blockIdx.x == 0 && threadIdx.x < NB) bcnt[threadIdx.x] = 0;
    int i = blockIdx.x * 256 + threadIdx.x;          // float4 index, exact grid 2.4M
    const int nu4 = N_USER * D / 4;
    float4 v = (i < nu4) ? ((const float4*)u)[i] : ((const float4*)it)[i - nu4];
    h2 a, b;
    a.x = (_Float16)v.x; a.y = (_Float16)v.y;
    b.x = (_Float16)v.z; b.y = (_Float16)v.w;
    ((uint2*)A16)[i] = make_uint2(__builtin_bit_cast(uint, a), __builtin_bit_cast(uint, b));
}

// ---------------- bucket histogram (LDS-aggregated) ----------------
__global__ __launch_bounds__(1024) void k_bhist(const int* __restrict__ rows,
                                                int* __restrict__ bcnt) {
    __shared__ int lcnt[NB];
    int tid = threadIdx.x;
    if (tid < NB) lcnt[tid] = 0;
    __syncthreads();
    int base = blockIdx.x * P1_PER;
    #pragma unroll
    for (int k = 0; k < 4; ++k) {
        int i = base + k * 1024 + tid;
        if (i < NNZ) atomicAdd(&lcnt[rows[i] >> BSHIFT], 1);
    }
    __syncthreads();
    if (tid < NB) atomicAdd(&bcnt[tid], lcnt[tid]);
}

// ---- bscan (block 3072) fused with gather0 (blocks 0..3071) ----
__global__ void k_bscan_gather(const int* __restrict__ bcnt, int* __restrict__ bptr,
                               int* __restrict__ bcur,
                               const float* __restrict__ u, const float* __restrict__ it,
                               const int* __restrict__ users, const int* __restrict__ pos,
                               const int* __restrict__ neg, float* __restrict__ out) {
    __shared__ int s[256];
    if (blockIdx.x == 3072) {                        // exclusive scan over NB counts
        int tid = threadIdx.x;
        int v = (tid < NB) ? bcnt[tid] : 0;
        s[tid] = v; __syncthreads();
        for (int off = 1; off < 256; off <<= 1) {
            int t = (tid >= off) ? s[tid - off] : 0;
            __syncthreads();
            s[tid] += t;
            __syncthreads();
        }
        if (tid < NB) { int ex = s[tid] - v; bptr[tid] = ex; bcur[tid] = ex; }
        if (tid == NB - 1) bptr[NB] = s[tid];
        return;
    }
    int lane = threadIdx.x & 63;
    int gi = blockIdx.x * 4 + (threadIdx.x >> 6);
    int g = gi >> 12, b = gi & 4095;
    const float* src = (g == 0) ? (u + (size_t)users[b] * D)
                                : (it + (size_t)((g == 1) ? pos[b] : neg[b]) * D);
    out[gi * 256 + lane] = src[lane];
}

// ---------------- pass 1: bin entries bucket-major ----------------
__global__ __launch_bounds__(1024) void k_binpass1(const int* __restrict__ rows,
                                                   const int* __restrict__ cols,
                                                   const float* __restrict__ vals,
                                                   int* __restrict__ bcur,
                                                   int2* __restrict__ bucketed) {
    __shared__ int lcnt[NB], lbase[NB];
    int tid = threadIdx.x;
    int base = blockIdx.x * P1_PER;
    if (tid < NB) lcnt[tid] = 0;
    __syncthreads();
    int r[4];
    #pragma unroll
    for (int k = 0; k < 4; ++k) {
        int i = base + k * 1024 + tid;
        r[k] = (i < NNZ) ? rows[i] : -1;
        if (r[k] >= 0) atomicAdd(&lcnt[r[k] >> BSHIFT], 1);
    }
    __syncthreads();
    if (tid < NB) { lbase[tid] = atomicAdd(&bcur[tid], lcnt[tid]); lcnt[tid] = 0; }
    __syncthreads();
    #pragma unroll
    for (int k = 0; k < 4; ++k) {
        int i = base + k * 1024 + tid;
        if (r[k] >= 0) {
            int b = r[k] >> BSHIFT;
            int off = atomicAdd(&lcnt[b], 1);
            bucketed[lbase[b] + off] =
                make_int2(((r[k] & 1023) << 18) | cols[i], __float_as_int(vals[i]));
        }
    }
}

// ---------------- pass 2: per-bucket CSR build ----------------
__global__ __launch_bounds__(1024) void k_binpass2(const int* __restrict__ bptr,
                                                   const int2* __restrict__ bucketed,
                                                   int* __restrict__ ptr,
                                                   int2* __restrict__ csr) {
    __shared__ int c0[1024], px[1024];
    int tid = threadIdx.x, b = blockIdx.x;
    int s = bptr[b], e = bptr[b + 1];
    c0[tid] = 0;
    __syncthreads();
    for (int i = s + tid; i < e; i += 1024) atomicAdd(&c0[bucketed[i].x >> 18], 1);
    __syncthreads();
    int v = c0[tid];
    px[tid] = v;
    __syncthreads();
    for (int off = 1; off < 1024; off <<= 1) {
        int t = (tid >= off) ? px[tid - off] : 0;
        __syncthreads();
        px[tid] += t;
        __syncthreads();
    }
    int ex = px[tid] - v;
    int r = (b << BSHIFT) + tid;
    if (r <= NTOT) ptr[r] = s + ex;
    px[tid] = ex;
    c0[tid] = 0;
    __syncthreads();
    for (int i = s + tid; i < e; i += 1024) {
        int2 e2 = bucketed[i];
        int lr = e2.x >> 18;
        int off = atomicAdd(&c0[lr], 1);
        csr[s + px[lr] + off] = make_int2(e2.x & 0x3FFFF, e2.y);
    }
}

// -------- SpMM (blocks < SPMM_BLKS) + fused normalized gather (blocks >=) --------
__global__ __launch_bounds__(256) void k_spmm(const int* __restrict__ ptr,
                                              const int2* __restrict__ csr,
                                              const ushort* __restrict__ E16,
                                              ushort* __restrict__ L16,
                                              const int* __restrict__ users,
                                              const int* __restrict__ pos,
                                              const int* __restrict__ neg,
                                              float* __restrict__ out, int layer) {
    int lane = threadIdx.x & 63;
    if (blockIdx.x >= SPMM_BLKS) {                   // gather of PREVIOUS layer output
        int gi = (blockIdx.x - SPMM_BLKS) * 4 + (threadIdx.x >> 6);
        int g = gi >> 12, b = gi & 4095;
        int src = (g == 0) ? users[b] : (N_USER + ((g == 1) ? pos[b] : neg[b]));
        float v = (float)__builtin_bit_cast(_Float16, E16[src * D + lane]);
        float ss = v * v;
        #pragma unroll
        for (int off = 32; off >= 1; off >>= 1) ss += __shfl_xor(ss, off, 64);
        float dnm = fmaxf(sqrtf(ss), 1e-12f);
        out[gi * 256 + layer * D + lane] = v / dnm;
        return;
    }
    int half = lane >> 5;
    int l32  = lane & 31;
    int r = __builtin_amdgcn_readfirstlane(blockIdx.x * 4 + (threadIdx.x >> 6));
    int start = ptr[r], end = ptr[r + 1];
    float acc0 = 0.f, acc1 = 0.f;
    const uint* E32 = (const uint*)E16;              // [c*32 + l32] = cols (2*l32, 2*l32+1)
    int j = start;
    for (; j + 15 < end; j += 16) {                  // 8 gather-lines in flight, all named
        int2 ea0 = csr[j + 0],  ea1 = csr[j + 1],  ea2 = csr[j + 2],  ea3 = csr[j + 3];
        int2 ea4 = csr[j + 4],  ea5 = csr[j + 5],  ea6 = csr[j + 6],  ea7 = csr[j + 7];
        int2 ea8 = csr[j + 8],  ea9 = csr[j + 9],  eaA = csr[j + 10], eaB = csr[j + 11];
        int2 eaC = csr[j + 12], eaD = csr[j + 13], eaE = csr[j + 14], eaF = csr[j + 15];
        int c0 = half ? ea1.x : ea0.x;
        int c1 = half ? ea3.x : ea2.x;
        int c2 = half ? ea5.x : ea4.x;
        int c3 = half ? ea7.x : ea6.x;
        int c4 = half ? ea9.x : ea8.x;
        int c5 = half ? eaB.x : eaA.x;
        int c6 = half ? eaD.x : eaC.x;
        int c7 = half ? eaF.x : eaE.x;
        uint u0 = E32[(c0 << 5) + l32];
        uint u1 = E32[(c1 << 5) + l32];
        uint u2 = E32[(c2 << 5) + l32];
        uint u3 = E32[(c3 << 5) + l32];
        uint u4 = E32[(c4 << 5) + l32];
        uint u5 = E32[(c5 << 5) + l32];
        uint u6 = E32[(c6 << 5) + l32];
        uint u7 = E32[(c7 << 5) + l32];
        float v0 = __int_as_float(half ? ea1.y : ea0.y);
        float v1 = __int_as_float(half ? ea3.y : ea2.y);
        float v2 = __int_as_float(half ? ea5.y : ea4.y);
        float v3 = __int_as_float(half ? ea7.y : ea6.y);
        float v4 = __int_as_float(half ? ea9.y : ea8.y);
        float v5 = __int_as_float(half ? eaB.y : eaA.y);
        float v6 = __int_as_float(half ? eaD.y : eaC.y);
        float v7 = __int_as_float(half ? eaF.y : eaE.y);
        h2 p0 = __builtin_bit_cast(h2, u0), p1 = __builtin_bit_cast(h2, u1);
        h2 p2 = __builtin_bit_cast(h2, u2), p3 = __builtin_bit_cast(h2, u3);
        h2 p4 = __builtin_bit_cast(h2, u4), p5 = __builtin_bit_cast(h2, u5);
        h2 p6 = __builtin_bit_cast(h2, u6), p7 = __builtin_bit_cast(h2, u7);
        acc0 += v0 * (float)p0.x;  acc1 += v0 * (float)p0.y;   // v_fma_mix_f32
        acc0 += v1 * (float)p1.x;  acc1 += v1 * (float)p1.y;
        acc0 += v2 * (float)p2.x;  acc1 += v2 * (float)p2.y;
        acc0 += v3 * (float)p3.x;  acc1 += v3 * (float)p3.y;
        acc0 += v4 * (float)p4.x;  acc1 += v4 * (float)p4.y;
        acc0 += v5 * (float)p5.x;  acc1 += v5 * (float)p5.y;
        acc0 += v6 * (float)p6.x;  acc1 += v6 * (float)p6.y;
        acc0 += v7 * (float)p7.x;  acc1 += v7 * (float)p7.y;
    }
    for (; j + 7 < end; j += 8) {
        int2 ea = csr[j + 0], eb = csr[j + 1];
        int2 ec = csr[j + 2], ed = csr[j + 3];
        int2 ee = csr[j + 4], ef = csr[j + 5];
        int2 eg = csr[j + 6], eh = csr[j + 7];
        int c0 = half ? eb.x : ea.x;
        int c1 = half ? ed.x : ec.x;
        int c2 = half ? ef.x : ee.x;
        int c3 = half ? eh.x : eg.x;
        uint u0 = E32[(c0 << 5) + l32];
        uint u1 = E32[(c1 << 5) + l32];
        uint u2 = E32[(c2 << 5) + l32];
        uint u3 = E32[(c3 << 5) + l32];
        float v0 = __int_as_float(half ? eb.y : ea.y);
        float v1 = __int_as_float(half ? ed.y : ec.y);
        float v2 = __int_as_float(half ? ef.y : ee.y);
        float v3 = __int_as_float(half ? eh.y : eg.y);
        h2 p0 = __builtin_bit_cast(h2, u0), p1 = __builtin_bit_cast(h2, u1);
        h2 p2 = __builtin_bit_cast(h2, u2), p3 = __builtin_bit_cast(h2, u3);
        acc0 += v0 * (float)p0.x;  acc1 += v0 * (float)p0.y;
        acc0 += v1 * (float)p1.x;  acc1 += v1 * (float)p1.y;
        acc0 += v2 * (float)p2.x;  acc1 += v2 * (float)p2.y;
        acc0 += v3 * (float)p3.x;  acc1 += v3 * (float)p3.y;
    }
    for (; j + 1 < end; j += 2) {
        int2 ea = csr[j], eb = csr[j + 1];
        int c   = half ? eb.x : ea.x;
        float v = __int_as_float(half ? eb.y : ea.y);
        h2 p = __builtin_bit_cast(h2, E32[(c << 5) + l32]);
        acc0 += v * (float)p.x;  acc1 += v * (float)p.y;
    }
    if (j < end) {
        int2 ea = csr[j];
        if (half == 0) {
            h2 p = __builtin_bit_cast(h2, E32[(ea.x << 5) + l32]);
            float v = __int_as_float(ea.y);
            acc0 += v * (float)p.x;  acc1 += v * (float)p.y;
        }
    }
    acc0 += __shfl_xor(acc0, 32, 64);
    acc1 += __shfl_xor(acc1, 32, 64);
    if (half == 0) {
        h2 o; o.x = (_Float16)acc0; o.y = (_Float16)acc1;
        ((uint*)L16)[(r << 5) + l32] = __builtin_bit_cast(uint, o);
    }
}

// ---- MFMA transform v3: per-wave coalesced LDS staging of L/E rows ----
// v_mfma_f32_16x16x16_f16: A lane l -> row l&15, k=(l>>4)*4+j;
// D lane l reg i -> row (l>>4)*4+i, col l&15.
#define SPITCH 36             // uints per staged row (32 data + 4 pad): 2-way banks
__global__ __launch_bounds__(256) void k_transform_mfma(
        const ushort* __restrict__ E16, const ushort* __restrict__ L16,
        const float* __restrict__ Wgc, const float* __restrict__ Wbi,
        const float* __restrict__ bb, ushort* __restrict__ O16, int n) {
    __shared__ _Float16 ldsW[2 * 16 * 256];               // 16KB
    __shared__ __align__(16) uint stage[4][2 * 16 * SPITCH];  // 18KB; per-wave L|E tiles
    int tid = threadIdx.x;

    #pragma unroll
    for (int m = 0; m < 2; ++m) {
        const float* W = m ? Wbi : Wgc;
        for (int idx = tid; idx < 4096; idx += 256) {
            int k = idx >> 6, nn = idx & 63;
            ldsW[(m * 16 + (k >> 4) * 4 + (nn >> 4)) * 256 + (nn & 15) * 16 + (k & 15)] =
                (_Float16)W[idx];
        }
    }
    __syncthreads();

    int l = tid & 63, w = tid >> 6;
    int g = l >> 4, r16 = l & 15;

    // B-fragments: one ds_read_b64 each, persistent in registers
    h4 bfrag[2][4][4];
    #pragma unroll
    for (int m = 0; m < 2; ++m)
        #pragma unroll
        for (int ks = 0; ks < 4; ++ks)
            #pragma unroll
            for (int nt = 0; nt < 4; ++nt)
                bfrag[m][ks][nt] =
                    *(const h4*)&ldsW[(m * 16 + ks * 4 + nt) * 256 + r16 * 16 + g * 4];

    int rowbase = blockIdx.x * 64 + w * 16;

    // ---- per-wave coalesced staging: 16 rows x 128B of L and E ----
    uint* sL = &stage[w][0];
    uint* sE = &stage[w][16 * SPITCH];
    {
        int sr = l >> 2;                     // 0..15 local row
        int ch = (l & 3) * 8;                // uint chunk
        int rg = min(rowbase + sr, n - 1);
        int gb = (rg << 5) + ch;
        uint4 la = *(const uint4*)&((const uint*)L16)[gb];
        uint4 lb = *(const uint4*)&((const uint*)L16)[gb + 4];
        uint4 ea = *(const uint4*)&((const uint*)E16)[gb];
        uint4 eb = *(const uint4*)&((const uint*)E16)[gb + 4];
        *(uint4*)&sL[sr * SPITCH + ch]     = la;
        *(uint4*)&sL[sr * SPITCH + ch + 4] = lb;
        *(uint4*)&sE[sr * SPITCH + ch]     = ea;
        *(uint4*)&sE[sr * SPITCH + ch + 4] = eb;
    }
    // wave-coherent: each wave only reads its own tile (LDS ops in-order per wave)

    h4 x1[4], x2[4];
    #pragma unroll
    for (int ks = 0; ks < 4; ++ks) {
        int si = r16 * SPITCH + ks * 8 + g * 2;
        uint2 lw = *(const uint2*)&sL[si];
        uint2 ew = *(const uint2*)&sE[si];
        h4 l4, e4;
        h2 la = __builtin_bit_cast(h2, lw.x), lb = __builtin_bit_cast(h2, lw.y);
        h2 ea = __builtin_bit_cast(h2, ew.x), eb = __builtin_bit_cast(h2, ew.y);
        l4[0] = la.x; l4[1] = la.y; l4[2] = lb.x; l4[3] = lb.y;
        e4[0] = ea.x; e4[1] = ea.y; e4[2] = eb.x; e4[3] = eb.y;
        x1[ks] = l4 + e4;                            // v_pk_add_f16
        x2[ks] = l4 * e4;                            // v_pk_mul_f16
    }

    f4 acc[4];
    #pragma unroll
    for (int nt = 0; nt < 4; ++nt) acc[nt] = (f4){0.f, 0.f, 0.f, 0.f};
    #pragma unroll
    for (int ks = 0; ks < 4; ++ks)
        #pragma unroll
        for (int nt = 0; nt < 4; ++nt)
            acc[nt] = __builtin_amdgcn_mfma_f32_16x16x16f16(x1[ks], bfrag[0][ks][nt],
                                                            acc[nt], 0, 0, 0);
    #pragma unroll
    for (int ks = 0; ks < 4; ++ks)
        #pragma unroll
        for (int nt = 0; nt < 4; ++nt)
            acc[nt] = __builtin_amdgcn_mfma_f32_16x16x16f16(x2[ks], bfrag[1][ks][nt],
                                                            acc[nt], 0, 0, 0);

    __syncthreads();                                 // stage region reused as ldsO

    // epilogue: bias + leaky -> f16 LDS tile (aliases stage[w]) -> coalesced store
    ushort* ow = (ushort*)&stage[w][0];              // 16 x 72 pitch tile
    #pragma unroll
    for (int nt = 0; nt < 4; ++nt) {
        int col = nt * 16 + r16;
        float bv = 2.f * bb[col];
        #pragma unroll
        for (int i = 0; i < 4; ++i) {
            float y = acc[nt][i] + bv;
            y = (y >= 0.f) ? y : NEG_SLOPE * y;
            ow[(g * 4 + i) * 72 + col] = __builtin_bit_cast(ushort, (_Float16)y);
        }
    }
    int lr = l >> 2;
    int rowg = rowbase + lr;
    if (rowg < n) {
        const ushort* src = &ow[lr * 72 + (l & 3) * 16];
        uint4 v0 = *(const uint4*)src;
        uint4 v1 = *(const uint4*)(src + 8);
        *(uint4*)&O16[rowg * D + (l & 3) * 16] = v0;
        *(uint4*)&O16[rowg * D + (l & 3) * 16 + 8] = v1;
    }
}

// ---------------- normalized gather (f16 ego), final layer ----------------
__global__ void k_gathern(const ushort* __restrict__ E16, const int* __restrict__ users,
                          const int* __restrict__ pos, const int* __restrict__ neg,
                          float* __restrict__ out, int layer) {
    int lane = threadIdx.x & 63;
    int gi = blockIdx.x * 4 + (threadIdx.x >> 6);
    int g = gi >> 12, b = gi & 4095;
    int src = (g == 0) ? users[b] : (N_USER + ((g == 1) ? pos[b] : neg[b]));
    float v = (float)__builtin_bit_cast(_Float16, E16[src * D + lane]);
    float ss = v * v;
    #pragma unroll
    for (int off = 32; off >= 1; off >>= 1) ss += __shfl_xor(ss, off, 64);
    float dnm = fmaxf(sqrtf(ss), 1e-12f);
    out[gi * 256 + layer * D + lane] = v / dnm;
}

extern "C" void kernel_launch(void* const* d_in, const int* in_sizes, int n_in,
                              void* d_out, int out_size, void* d_ws, size_t ws_size,
                              hipStream_t stream) {
    const float* user_emb = (const float*)d_in[0];
    const float* item_emb = (const float*)d_in[1];
    const float* W_gc     = (const float*)d_in[2];
    const float* W_bi     = (const float*)d_in[3];
    const float* b_bi     = (const float*)d_in[4];
    const float* vals     = (const float*)d_in[5];
    const int*   rows     = (const int*)d_in[6];
    const int*   cols     = (const int*)d_in[7];
    const int*   users    = (const int*)d_in[8];
    const int*   pos      = (const int*)d_in[9];
    const int*   neg      = (const int*)d_in[10];
    float* out = (float*)d_out;

    char* ws = (char*)d_ws;
    size_t off = 0;
    auto alloc = [&](size_t b) { void* p = ws + off; off += (b + 255) & ~(size_t)255; return p; };
    ushort* Ea  = (ushort*)alloc((size_t)NTOT * D * 2);   // f16 ego (ping)
    ushort* Eb  = (ushort*)alloc((size_t)NTOT * D * 2);   // f16 ego (pong)
    ushort* L16 = (ushort*)alloc((size_t)NTOT * D * 2);   // f16 spmm output
    int2*   csr = (int2*)  alloc((size_t)NNZ * 8);
    int*    ptr = (int*)   alloc((size_t)(NTOT + 64) * 4);
    int*    bptr= (int*)   alloc((NB + 1) * 4);
    int*    bcnt= (int*)   alloc(NB * 4);
    int*    bcur= (int*)   alloc(NB * 4);
    int2*   bucketed = (int2*)alloc((size_t)NNZ * 8);     // dead after binpass2
    (void)ws_size;

    hipLaunchKernelGGL(k_concat16,    dim3(9375), dim3(256),  0, stream, user_emb, item_emb, Ea, bcnt);
    hipLaunchKernelGGL(k_bhist,       dim3(NBLK1),dim3(1024), 0, stream, rows, bcnt);
    hipLaunchKernelGGL(k_bscan_gather,dim3(3073), dim3(256),  0, stream, bcnt, bptr, bcur,
                       user_emb, item_emb, users, pos, neg, out);
    hipLaunchKernelGGL(k_binpass1,    dim3(NBLK1),dim3(1024), 0, stream, rows, cols, vals, bcur, bucketed);
    hipLaunchKernelGGL(k_binpass2,    dim3(NB),   dim3(1024), 0, stream, bptr, bucketed, ptr, csr);

    ushort* cur = Ea; ushort* nxt = Eb;
    for (int k = 0; k < 3; ++k) {
        int grid = (k == 0) ? SPMM_BLKS : SPMM_BLKS + 3072;   // fuse prev layer's gather
        hipLaunchKernelGGL(k_spmm, dim3(grid), dim3(256), 0, stream, ptr, csr, cur, L16,
                           users, pos, neg, out, k);
        hipLaunchKernelGGL(k_transform_mfma, dim3(NROWBLK), dim3(256), 0, stream, cur, L16,
                           W_gc + k * 4096, W_bi + k * 4096, b_bi + k * 64, nxt, NTOT);
        ushort* t = cur; cur = nxt; nxt = t;
    }
    hipLaunchKernelGGL(k_gathern, dim3(3072), dim3(256), 0, stream, cur, users, pos, neg, out, 3);
}